// Round 18
// baseline (208.273 us; speedup 1.0000x reference)
//
#include <hip/hip_runtime.h>

// OnLSTMCell fused pipeline for MI355X (gfx950).
// B=8192, input=1024, hidden=1024, level=64, d_in=2048.
// ws layout (bytes):
//   A_HI   @ 0          : u16[8192*2048]  (32 MB)   bf16(concat(input,h_prev))
//   W_HI   @ 67108864   : u16[4224*2048]  (16.5 MB) rows 0..4095 gate-interleaved (n=j*4+gate), 4096..4223 = W_level
//   WLEV_LO@ 84410368   : u16[128*2048]   (0.5 MB)
//   IH     @ 118489088  : f32[8192*64]    (2 MB)
//   FH     @ 120586240  : f32[8192*64]    (2 MB)

typedef unsigned short u16;
typedef __attribute__((ext_vector_type(8))) short bf16x8;
typedef __attribute__((ext_vector_type(8))) short s8v;
typedef __attribute__((ext_vector_type(4))) float f32x4;
typedef __attribute__((ext_vector_type(4))) float v4f;

#define GLDS(g, l) __builtin_amdgcn_global_load_lds(                      \
    (const __attribute__((address_space(1))) void*)(g),                   \
    (__attribute__((address_space(3))) void*)(l), 16, 0, 0)

__device__ __forceinline__ u16 f2bf(float x) {
  unsigned u = __builtin_bit_cast(unsigned, x);
  u += 0x7FFFu + ((u >> 16) & 1u);
  return (u16)(u >> 16);
}
__device__ __forceinline__ float bf2f(u16 h) {
  unsigned u = ((unsigned)h) << 16;
  return __builtin_bit_cast(float, u);
}
__device__ __forceinline__ float fsig(float x) { return 1.0f / (1.0f + __expf(-x)); }
__device__ __forceinline__ float ftanhf(float x) { float e = __expf(2.0f * x); return 1.0f - 2.0f / (e + 1.0f); }

// ---------------------------------------------------------------- convert ---
// (unchanged from r14/r15)
__global__ __launch_bounds__(256) void k_convert(
    const float* __restrict__ inp, const float* __restrict__ hprev,
    const float* __restrict__ wl, const float* __restrict__ wlev,
    u16* __restrict__ Ahi, u16* __restrict__ Whi, u16* __restrict__ Wlo)
{
  const int GA = (8192 * 2048) / 8;
  const int GW = (4224 * 2048) / 8;
  for (int gi = blockIdx.x * 256 + threadIdx.x; gi < GA + GW; gi += gridDim.x * 256) {
    if (gi < GA) {
      int e = gi << 3; int row = e >> 11, col = e & 2047;
      const float* src = (col < 1024) ? (inp + row * 1024 + col)
                                      : (hprev + row * 1024 + (col - 1024));
      v4f a = *(const v4f*)src, b = *(const v4f*)(src + 4);
      float vv[8] = {a.x, a.y, a.z, a.w, b.x, b.y, b.z, b.w};
      s8v hi;
#pragma unroll
      for (int j = 0; j < 8; ++j) hi[j] = (short)f2bf(vv[j]);
      *(s8v*)(Ahi + e) = hi;
    } else {
      int e = (gi - GA) << 3; int n = e >> 11, k = e & 2047;
      const float* src;
      if (n < 4096) { int j = n >> 2, g = n & 3; src = wl + (size_t)((g << 10) | j) * 2048 + k; }
      else          { src = wlev + (size_t)(n - 4096) * 2048 + k; }
      v4f a = *(const v4f*)src, b = *(const v4f*)(src + 4);
      float vv[8] = {a.x, a.y, a.z, a.w, b.x, b.y, b.z, b.w};
      s8v hi, lo;
#pragma unroll
      for (int j = 0; j < 8; ++j) {
        u16 h = f2bf(vv[j]);
        hi[j] = (short)h;
        lo[j] = (short)f2bf(vv[j] - bf2f(h));
      }
      *(s8v*)(Whi + e) = hi;
      if (n >= 4096) *(s8v*)(Wlo + (size_t)(n - 4096) * 2048 + k) = lo;
    }
  }
}

// ------------------- level GEMM + softmax + cumsums, fused (full-K) ---------
// (unchanged from r15)
__global__ __launch_bounds__(256) void k_level_fused(
    const u16* __restrict__ Ahi, const u16* __restrict__ Whi,
    const u16* __restrict__ Wlo, float* __restrict__ ih, float* __restrict__ fh)
{
  __shared__ __align__(16) u16 smem[2 * 18432];   // 72 KB
  const int tid = threadIdx.x, lane = tid & 63, wid = tid >> 6;
  const int c16 = lane & 15, r16 = lane >> 4;
  const int r0 = blockIdx.x << 5;

  const int row_t = tid >> 3;
  const int xk8 = ((tid & 7) ^ (row_t & 7)) << 3;
  const u16* pa_s  = Ahi + (size_t)(r0 + row_t) * 2048 + xk8;
  const u16* pbh_s = Whi + (size_t)(4096 + row_t) * 2048 + xk8;
  const u16* pbl_s = Wlo + (size_t)row_t * 2048 + xk8;
  char* const ldsW = (char*)smem + (wid << 10);

  const int sl0 = ((r16 ^ (c16 & 7)) << 3);
  const int sl1 = (((4 | r16) ^ (c16 & 7)) << 3);

  f32x4 acc[2][2] = {};

#define LSTAGE(kt, buf) do {                                           \
    char* d_ = ldsW + (buf) * 36864;                                   \
    const int ko_ = (kt) * 64;                                         \
    GLDS(pa_s + ko_, d_);                                              \
    GLDS(pbh_s + ko_,          d_ + 4096);                             \
    GLDS(pbh_s + ko_ + 65536,  d_ + 8192);                             \
    GLDS(pbh_s + ko_ + 131072, d_ + 12288);                            \
    GLDS(pbh_s + ko_ + 196608, d_ + 16384);                            \
    GLDS(pbl_s + ko_,          d_ + 20480);                            \
    GLDS(pbl_s + ko_ + 65536,  d_ + 24576);                            \
    GLDS(pbl_s + ko_ + 131072, d_ + 28672);                            \
    GLDS(pbl_s + ko_ + 196608, d_ + 32768);                            \
  } while (0)

#define LCOMP(buf) do {                                                \
    const u16* bp_ = smem + (buf) * 18432;                             \
    _Pragma("unroll")                                                  \
    for (int ks = 0; ks < 2; ++ks) {                                   \
      const int sx_ = ks ? sl1 : sl0;                                  \
      bf16x8 ah[2];                                                    \
      _Pragma("unroll")                                                \
      for (int mi = 0; mi < 2; ++mi)                                   \
        ah[mi] = *(const bf16x8*)(bp_ + (mi * 16 + c16) * 64 + sx_);   \
      _Pragma("unroll")                                                \
      for (int j = 0; j < 2; ++j) {                                    \
        int br_ = (wid * 32 + j * 16 + c16) * 64 + sx_;                \
        bf16x8 bh = *(const bf16x8*)(bp_ + 2048 + br_);                \
        bf16x8 bl = *(const bf16x8*)(bp_ + 10240 + br_);               \
        _Pragma("unroll")                                              \
        for (int mi = 0; mi < 2; ++mi) {                               \
          acc[mi][j] = __builtin_amdgcn_mfma_f32_16x16x32_bf16(ah[mi], bh, acc[mi][j], 0, 0, 0); \
          acc[mi][j] = __builtin_amdgcn_mfma_f32_16x16x32_bf16(ah[mi], bl, acc[mi][j], 0, 0, 0); \
        }                                                              \
      }                                                                \
    }                                                                  \
  } while (0)

#define LTILE(t, buf, dostage) do {                                    \
    if (dostage) LSTAGE((t) + 1, (buf) ^ 1);                           \
    if (dostage) asm volatile("s_waitcnt vmcnt(9)" ::: "memory");      \
    else         asm volatile("s_waitcnt vmcnt(0)" ::: "memory");      \
    __builtin_amdgcn_s_barrier();                                      \
    LCOMP(buf);                                                        \
    __builtin_amdgcn_s_barrier();                                      \
  } while (0)

  LSTAGE(0, 0);
  for (int u = 0; u < 15; ++u) {
    LTILE(2 * u, 0, 1);
    LTILE(2 * u + 1, 1, 1);
  }
  LTILE(30, 0, 1);
  LTILE(31, 1, 0);
#undef LTILE
#undef LCOMP
#undef LSTAGE

  float* epi = (float*)smem;
#pragma unroll
  for (int mi = 0; mi < 2; ++mi)
#pragma unroll
    for (int j = 0; j < 2; ++j)
#pragma unroll
      for (int r = 0; r < 4; ++r)
        epi[(mi * 16 + r16 * 4 + r) * 128 + wid * 32 + j * 16 + c16] = acc[mi][j][r];
  __syncthreads();

  for (int rr = 0; rr < 8; ++rr) {
    int row = wid * 8 + rr;
    float vi = epi[row * 128 + lane];
    float vf = epi[row * 128 + 64 + lane];
    float mi = vi, mf = vf;
#pragma unroll
    for (int d = 1; d < 64; d <<= 1) {
      mi = fmaxf(mi, __shfl_xor(mi, d, 64));
      mf = fmaxf(mf, __shfl_xor(mf, d, 64));
    }
    float ei = __expf(vi - mi), ef = __expf(vf - mf);
    float si = ei, sf = ef;
#pragma unroll
    for (int d = 1; d < 64; d <<= 1) {
      si += __shfl_xor(si, d, 64);
      sf += __shfl_xor(sf, d, 64);
    }
    float pi = ei / si, pf = ef / sf;
    float ci = pi, cf = pf;
#pragma unroll
    for (int d = 1; d < 64; d <<= 1) {
      float t = __shfl_up(ci, d, 64); if (lane >= d) ci += t;
      float uu = __shfl_up(cf, d, 64); if (lane >= d) cf += uu;
    }
    int rowg = r0 + row;
    ih[(rowg << 6) + lane] = 1.0f - (ci - pi);
    fh[(rowg << 6) + lane] = cf;
  }
}

// -------------------------------------- main gates GEMM + fused epilogue ---
// r18: r12's PROVEN SLICE RHYTHM at 256x256 geometry (the untested cell).
// 512 thr = 8 waves (2M x 4N), wave-tile 128x64 (acc[8][4] = 128 regs,
// launch_bounds(512,2) -> 2 waves/SIMD). Intensity 42.7 FLOP/LDS-byte
// (12 b128 reads per 32 MFMA vs r12's 12:16): per-CU slice LDS ~350 cyc
// vs MFMA 1242 cyc -> MFMA-dominated even serialized. LDS: 3 slots x
// (A 256x32 + B 256x32) = 96 KB -> 1 block/CU (LDS traffic no longer
// binds; block-TLP not needed). Stage = 4 GLDS (A 2 chunks + B 2);
// vmcnt(4) ledger: at slice s after STAGE(s+2), outstanding =
// stage(s+1)(4) + stage(s+2)(4) -> forces stage(s+1) before barrier(s),
// which precedes reads(s+1). WAR: stage(s+2) overwrites slot (s-1)%3,
// whose reads were consumed by MFMA(s-1) before end-barrier(s-1). Never
// vmcnt(0) in-loop. 2-way swizzle both sides (r12 math verbatim).
// XCD map: 512 blocks = 8 x 64, cm fast (r3-proven, FETCH ~197 MB).
__global__ __launch_bounds__(512, 2) void k_gemm_main(
    const u16* __restrict__ Ab, const u16* __restrict__ Wb,
    const float* __restrict__ cprev, const float* __restrict__ ihp,
    const float* __restrict__ fhp, float* __restrict__ out)
{
  __shared__ __align__(16) u16 smem[49152];        // 96 KB; epi reuses 64 KB
  const int tid = threadIdx.x, lane = tid & 63, wid = tid >> 6;
  const int wm = wid >> 2, wn = wid & 3;           // 2M x 4N wave grid
  const int c16 = lane & 15, r16 = lane >> 4;

  // cm-fast XCD swizzle: 512 blocks = 8 XCD x 64; per XCD rm in 4 values
  // (4 MB A L2-resident), cm fast (W re-reads absorbed by L3).
  const int bx = blockIdx.x;
  const int nb = (bx & 7) * 64 + (bx >> 3);
  const int rm = nb >> 4, cm = nb & 15;            // 32 row x 16 col tiles

  // staging: thread -> (row sr=tid>>2 per 128-row chunk, 16B slot slq);
  // source pre-permuted (slq ^ (sr>>1)&3) so linear GLDS dest is swizzled.
  const int sr = tid >> 2;
  const int slq = tid & 3;
  const int xk = (slq ^ ((sr >> 1) & 3)) << 3;
  const u16* pa = Ab + (size_t)(rm * 256 + sr) * 2048 + xk;
  const u16* pb = Wb + (size_t)(cm * 256 + sr) * 2048 + xk;
  char* const ldsW = (char*)smem + (wid << 10);    // wave base within chunk

  // ds_read offsets (u16): slot*16384 + chunk*4096 + row*32 + swz slot.
  const int xsl = (r16 ^ ((c16 >> 1) & 3)) << 3;
  const int base_a = wm * 4096 + c16 * 32 + xsl;                      // +i*512 (i=0..7)
  const int base_b = 8192 + (wn >> 1) * 4096 + ((wn & 1) * 64 + c16) * 32 + xsl; // +j*512 (j=0..3)

  f32x4 acc[8][4] = {};

#define STAGE4(slice, slot) do {                                       \
    const u16* sa_ = pa + (slice) * 32;                                \
    const u16* sb_ = pb + (slice) * 32;                                \
    char* d_ = ldsW + (slot) * 32768;                                  \
    GLDS(sa_, d_);           GLDS(sa_ + 262144, d_ + 8192);            \
    GLDS(sb_, d_ + 16384);   GLDS(sb_ + 262144, d_ + 24576);           \
  } while (0)

#define SLICE(s, slot, dostage) do {                                   \
    bf16x8 aX[8], bS[4];                                               \
    _Pragma("unroll")                                                  \
    for (int i = 0; i < 8; ++i)                                        \
      aX[i] = *(const bf16x8*)(smem + (slot) * 16384 + base_a + i * 512); \
    _Pragma("unroll")                                                  \
    for (int j = 0; j < 4; ++j)                                        \
      bS[j] = *(const bf16x8*)(smem + (slot) * 16384 + base_b + j * 512); \
    if (dostage) STAGE4(((s) + 2) & 63, ((s) + 2) % 3);                \
    asm volatile("s_waitcnt vmcnt(4)" ::: "memory");                   \
    __builtin_amdgcn_s_barrier();                                      \
    asm volatile("s_waitcnt lgkmcnt(0)" ::: "memory");                 \
    _Pragma("unroll")                                                  \
    for (int i = 0; i < 8; ++i)                                        \
      _Pragma("unroll")                                                \
      for (int j = 0; j < 4; ++j)                                      \
        acc[i][j] = __builtin_amdgcn_mfma_f32_16x16x32_bf16(           \
            aX[i], bS[j], acc[i][j], 0, 0, 0);                         \
    __builtin_amdgcn_s_barrier();                                      \
  } while (0)

  // prologue: slices 0,1 -> slots 0,1; vmcnt(4) forces slice 0 complete
  // (leaves slice 1's 4 loads in flight); barrier publishes.
  STAGE4(0, 0); STAGE4(1, 1);
  asm volatile("s_waitcnt vmcnt(4)" ::: "memory");
  __builtin_amdgcn_s_barrier();

  for (int u = 0; u < 21; ++u) {                    // slices 0..62
    const int s0 = u * 3;
    SLICE(s0 + 0, 0, 1);
    SLICE(s0 + 1, 1, 1);
    SLICE(s0 + 2, 2, 1);
  }
  SLICE(63, 0, 0);                                  // peeled last slice
#undef SLICE
#undef STAGE4

  // drain wrap-dummy stage before LDS reuse
  asm volatile("s_waitcnt vmcnt(0)" ::: "memory");
  __builtin_amdgcn_s_barrier();

  // ---- fused ON-LSTM epilogue: 4 passes, epi = f32[64][256] (64 KB).
  // Pass p covers tile rows p*64..p*64+63: waves wm == p>>1 write
  // acc[(p&1)*4 + iq][j][r] (literal indices, rule #20). Consumer: each
  // thread 2 items x 4 consecutive hidden units -> v4f h/c stores
  // (256-B contiguous lines per 16 threads; r11-proven WRITE=64MB).
  float* epi = (float*)smem;
#define EPIPASS(p) do {                                                \
    if (wm == ((p) >> 1)) {                                            \
      _Pragma("unroll")                                                \
      for (int iq = 0; iq < 4; ++iq)                                   \
        _Pragma("unroll")                                              \
        for (int j = 0; j < 4; ++j)                                    \
          _Pragma("unroll")                                            \
          for (int r = 0; r < 4; ++r) {                                \
            float v = acc[((p) & 1) * 4 + iq][j][r];                   \
            v = ((c16 & 3) == 3) ? ftanhf(v) : fsig(v);                \
            epi[(iq * 16 + r16 * 4 + r) * 256 + wn * 64 + j * 16 + c16] = v; \
          }                                                            \
    }                                                                  \
    __syncthreads();                                                   \
    _Pragma("unroll")                                                  \
    for (int e = 0; e < 2; ++e) {                                      \
      int idx = (e << 9) + tid;                                        \
      int m = idx >> 4, q = idx & 15;                                  \
      const float* g4 = epi + m * 256 + q * 16;                        \
      int rowg = rm * 256 + (p) * 64 + m;                              \
      int jgb = cm * 64 + q * 4;                                       \
      int lv = jgb >> 4;                                               \
      float vih = ihp[(rowg << 6) + lv], vfh = fhp[(rowg << 6) + lv];  \
      float wq = vih * vfh;                                            \
      v4f cp4 = *(const v4f*)(cprev + rowg * 1024 + jgb);              \
      float cpv[4] = {cp4.x, cp4.y, cp4.z, cp4.w};                     \
      v4f hv, cv;                                                      \
      _Pragma("unroll")                                                \
      for (int t = 0; t < 4; ++t) {                                    \
        v4f g = *(const v4f*)(g4 + t * 4);                             \
        float iv = g.x, fv = g.y, ov = g.z, gv = g.w;                  \
        float cpx = cpv[t];                                            \
        float c = wq * (fv * cpx + iv * gv) + (vfh - wq) * cpx + (vih - wq) * gv; \
        float h = ov * ftanhf(c);                                      \
        hv[t] = h; cv[t] = c;                                          \
      }                                                                \
      *(v4f*)(out + rowg * 1024 + jgb) = hv;                           \
      *(v4f*)(out + 8388608 + rowg * 1024 + jgb) = cv;                 \
    }                                                                  \
    __syncthreads();                                                   \
  } while (0)
  EPIPASS(0); EPIPASS(1); EPIPASS(2); EPIPASS(3);
#undef EPIPASS
}

// -------------------------------------------------------------- launcher ---
extern "C" void kernel_launch(void* const* d_in, const int* in_sizes, int n_in,
                              void* d_out, int out_size, void* d_ws, size_t ws_size,
                              hipStream_t stream) {
  (void)in_sizes; (void)n_in; (void)out_size; (void)ws_size;
  const float* inp   = (const float*)d_in[0];
  const float* hprev = (const float*)d_in[1];
  const float* cprev = (const float*)d_in[2];
  const float* wl    = (const float*)d_in[3];
  const float* wlev  = (const float*)d_in[4];
  float* out = (float*)d_out;
  char* ws = (char*)d_ws;

  u16* Ahi  = (u16*)(ws);
  u16* Whi  = (u16*)(ws + 67108864);
  u16* Wlo  = (u16*)(ws + 84410368);
  float* ih   = (float*)(ws + 118489088);
  float* fh   = (float*)(ws + 120586240);

  k_convert<<<dim3(2048), dim3(256), 0, stream>>>(inp, hprev, wl, wlev, Ahi, Whi, Wlo);
  k_level_fused<<<dim3(256), dim3(256), 0, stream>>>(Ahi, Whi, Wlo, ih, fh);
  k_gemm_main<<<dim3(512), dim3(512), 0, stream>>>(Ahi, Whi, cprev, ih, fh, out);
}

// Round 19
// 203.189 us; speedup vs baseline: 1.0250x; 1.0250x over previous
//
#include <hip/hip_runtime.h>

// OnLSTMCell fused pipeline for MI355X (gfx950).
// B=8192, input=1024, hidden=1024, level=64, d_in=2048.
// ws layout (bytes):
//   A_HI   @ 0          : u16[8192*2048]  (32 MB)   bf16(concat(input,h_prev))
//   W_HI   @ 67108864   : u16[4224*2048]  (16.5 MB) rows 0..4095 gate-interleaved (n=j*4+gate), 4096..4223 = W_level
//   WLEV_LO@ 84410368   : u16[128*2048]   (0.5 MB)
//   IH     @ 118489088  : f32[8192*64]    (2 MB)
//   FH     @ 120586240  : f32[8192*64]    (2 MB)
// FINAL CONFIG (r19 = r15 verbatim, best verified: 204.07 us total;
// k_gemm_main 169 us / MfmaUtil 37% — optimum of 10 schedule variants).

typedef unsigned short u16;
typedef __attribute__((ext_vector_type(8))) short bf16x8;
typedef __attribute__((ext_vector_type(8))) short s8v;
typedef __attribute__((ext_vector_type(4))) float f32x4;
typedef __attribute__((ext_vector_type(4))) float v4f;

#define GLDS(g, l) __builtin_amdgcn_global_load_lds(                      \
    (const __attribute__((address_space(1))) void*)(g),                   \
    (__attribute__((address_space(3))) void*)(l), 16, 0, 0)

__device__ __forceinline__ u16 f2bf(float x) {
  unsigned u = __builtin_bit_cast(unsigned, x);
  u += 0x7FFFu + ((u >> 16) & 1u);
  return (u16)(u >> 16);
}
__device__ __forceinline__ float bf2f(u16 h) {
  unsigned u = ((unsigned)h) << 16;
  return __builtin_bit_cast(float, u);
}
__device__ __forceinline__ float fsig(float x) { return 1.0f / (1.0f + __expf(-x)); }
__device__ __forceinline__ float ftanhf(float x) { float e = __expf(2.0f * x); return 1.0f - 2.0f / (e + 1.0f); }

// ---------------------------------------------------------------- convert ---
__global__ __launch_bounds__(256) void k_convert(
    const float* __restrict__ inp, const float* __restrict__ hprev,
    const float* __restrict__ wl, const float* __restrict__ wlev,
    u16* __restrict__ Ahi, u16* __restrict__ Whi, u16* __restrict__ Wlo)
{
  const int GA = (8192 * 2048) / 8;
  const int GW = (4224 * 2048) / 8;
  for (int gi = blockIdx.x * 256 + threadIdx.x; gi < GA + GW; gi += gridDim.x * 256) {
    if (gi < GA) {
      int e = gi << 3; int row = e >> 11, col = e & 2047;
      const float* src = (col < 1024) ? (inp + row * 1024 + col)
                                      : (hprev + row * 1024 + (col - 1024));
      v4f a = *(const v4f*)src, b = *(const v4f*)(src + 4);
      float vv[8] = {a.x, a.y, a.z, a.w, b.x, b.y, b.z, b.w};
      s8v hi;
#pragma unroll
      for (int j = 0; j < 8; ++j) hi[j] = (short)f2bf(vv[j]);
      *(s8v*)(Ahi + e) = hi;
    } else {
      int e = (gi - GA) << 3; int n = e >> 11, k = e & 2047;
      const float* src;
      if (n < 4096) { int j = n >> 2, g = n & 3; src = wl + (size_t)((g << 10) | j) * 2048 + k; }
      else          { src = wlev + (size_t)(n - 4096) * 2048 + k; }
      v4f a = *(const v4f*)src, b = *(const v4f*)(src + 4);
      float vv[8] = {a.x, a.y, a.z, a.w, b.x, b.y, b.z, b.w};
      s8v hi, lo;
#pragma unroll
      for (int j = 0; j < 8; ++j) {
        u16 h = f2bf(vv[j]);
        hi[j] = (short)h;
        lo[j] = (short)f2bf(vv[j] - bf2f(h));
      }
      *(s8v*)(Whi + e) = hi;
      if (n >= 4096) *(s8v*)(Wlo + (size_t)(n - 4096) * 2048 + k) = lo;
    }
  }
}

// ------------------- level GEMM + softmax + cumsums, fused (full-K) ---------
__global__ __launch_bounds__(256) void k_level_fused(
    const u16* __restrict__ Ahi, const u16* __restrict__ Whi,
    const u16* __restrict__ Wlo, float* __restrict__ ih, float* __restrict__ fh)
{
  __shared__ __align__(16) u16 smem[2 * 18432];   // 72 KB
  const int tid = threadIdx.x, lane = tid & 63, wid = tid >> 6;
  const int c16 = lane & 15, r16 = lane >> 4;
  const int r0 = blockIdx.x << 5;

  const int row_t = tid >> 3;
  const int xk8 = ((tid & 7) ^ (row_t & 7)) << 3;
  const u16* pa_s  = Ahi + (size_t)(r0 + row_t) * 2048 + xk8;
  const u16* pbh_s = Whi + (size_t)(4096 + row_t) * 2048 + xk8;
  const u16* pbl_s = Wlo + (size_t)row_t * 2048 + xk8;
  char* const ldsW = (char*)smem + (wid << 10);

  const int sl0 = ((r16 ^ (c16 & 7)) << 3);
  const int sl1 = (((4 | r16) ^ (c16 & 7)) << 3);

  f32x4 acc[2][2] = {};

#define LSTAGE(kt, buf) do {                                           \
    char* d_ = ldsW + (buf) * 36864;                                   \
    const int ko_ = (kt) * 64;                                         \
    GLDS(pa_s + ko_, d_);                                              \
    GLDS(pbh_s + ko_,          d_ + 4096);                             \
    GLDS(pbh_s + ko_ + 65536,  d_ + 8192);                             \
    GLDS(pbh_s + ko_ + 131072, d_ + 12288);                            \
    GLDS(pbh_s + ko_ + 196608, d_ + 16384);                            \
    GLDS(pbl_s + ko_,          d_ + 20480);                            \
    GLDS(pbl_s + ko_ + 65536,  d_ + 24576);                            \
    GLDS(pbl_s + ko_ + 131072, d_ + 28672);                            \
    GLDS(pbl_s + ko_ + 196608, d_ + 32768);                            \
  } while (0)

#define LCOMP(buf) do {                                                \
    const u16* bp_ = smem + (buf) * 18432;                             \
    _Pragma("unroll")                                                  \
    for (int ks = 0; ks < 2; ++ks) {                                   \
      const int sx_ = ks ? sl1 : sl0;                                  \
      bf16x8 ah[2];                                                    \
      _Pragma("unroll")                                                \
      for (int mi = 0; mi < 2; ++mi)                                   \
        ah[mi] = *(const bf16x8*)(bp_ + (mi * 16 + c16) * 64 + sx_);   \
      _Pragma("unroll")                                                \
      for (int j = 0; j < 2; ++j) {                                    \
        int br_ = (wid * 32 + j * 16 + c16) * 64 + sx_;                \
        bf16x8 bh = *(const bf16x8*)(bp_ + 2048 + br_);                \
        bf16x8 bl = *(const bf16x8*)(bp_ + 10240 + br_);               \
        _Pragma("unroll")                                              \
        for (int mi = 0; mi < 2; ++mi) {                               \
          acc[mi][j] = __builtin_amdgcn_mfma_f32_16x16x32_bf16(ah[mi], bh, acc[mi][j], 0, 0, 0); \
          acc[mi][j] = __builtin_amdgcn_mfma_f32_16x16x32_bf16(ah[mi], bl, acc[mi][j], 0, 0, 0); \
        }                                                              \
      }                                                                \
    }                                                                  \
  } while (0)

#define LTILE(t, buf, dostage) do {                                    \
    if (dostage) LSTAGE((t) + 1, (buf) ^ 1);                           \
    if (dostage) asm volatile("s_waitcnt vmcnt(9)" ::: "memory");      \
    else         asm volatile("s_waitcnt vmcnt(0)" ::: "memory");      \
    __builtin_amdgcn_s_barrier();                                      \
    LCOMP(buf);                                                        \
    __builtin_amdgcn_s_barrier();                                      \
  } while (0)

  LSTAGE(0, 0);
  for (int u = 0; u < 15; ++u) {
    LTILE(2 * u, 0, 1);
    LTILE(2 * u + 1, 1, 1);
  }
  LTILE(30, 0, 1);
  LTILE(31, 1, 0);
#undef LTILE
#undef LCOMP
#undef LSTAGE

  float* epi = (float*)smem;
#pragma unroll
  for (int mi = 0; mi < 2; ++mi)
#pragma unroll
    for (int j = 0; j < 2; ++j)
#pragma unroll
      for (int r = 0; r < 4; ++r)
        epi[(mi * 16 + r16 * 4 + r) * 128 + wid * 32 + j * 16 + c16] = acc[mi][j][r];
  __syncthreads();

  for (int rr = 0; rr < 8; ++rr) {
    int row = wid * 8 + rr;
    float vi = epi[row * 128 + lane];
    float vf = epi[row * 128 + 64 + lane];
    float mi = vi, mf = vf;
#pragma unroll
    for (int d = 1; d < 64; d <<= 1) {
      mi = fmaxf(mi, __shfl_xor(mi, d, 64));
      mf = fmaxf(mf, __shfl_xor(mf, d, 64));
    }
    float ei = __expf(vi - mi), ef = __expf(vf - mf);
    float si = ei, sf = ef;
#pragma unroll
    for (int d = 1; d < 64; d <<= 1) {
      si += __shfl_xor(si, d, 64);
      sf += __shfl_xor(sf, d, 64);
    }
    float pi = ei / si, pf = ef / sf;
    float ci = pi, cf = pf;
#pragma unroll
    for (int d = 1; d < 64; d <<= 1) {
      float t = __shfl_up(ci, d, 64); if (lane >= d) ci += t;
      float uu = __shfl_up(cf, d, 64); if (lane >= d) cf += uu;
    }
    int rowg = r0 + row;
    ih[(rowg << 6) + lane] = 1.0f - (ci - pi);
    fh[(rowg << 6) + lane] = cf;
  }
}

// -------------------------------------- main gates GEMM + fused epilogue ---
// r12 structure (verified optimum): 256x128 tile, 8 waves 4Mx2N (64x64
// wave-tiles), 3-slot 72KB LDS, 2 blocks/CU, cm-fast XCD map, vmcnt(3)
// ledger, no setprio, coalesced v4f epilogue.
__global__ __launch_bounds__(512, 4) void k_gemm_main(
    const u16* __restrict__ Ab, const u16* __restrict__ Wb,
    const float* __restrict__ cprev, const float* __restrict__ ihp,
    const float* __restrict__ fhp, float* __restrict__ out)
{
  __shared__ __align__(16) u16 smem[36864];        // 72 KB; epi reuses 64 KB
  const int tid = threadIdx.x, lane = tid & 63, wid = tid >> 6;
  const int wm = wid >> 1, wn = wid & 1;           // 4M x 2N wave grid
  const int c16 = lane & 15, r16 = lane >> 4;

  const int bx = blockIdx.x;
  const int nb = (bx & 7) * 128 + (bx >> 3);
  const int rm = nb >> 5, cm = nb & 31;            // rm slow, cm fast

  const int sr = tid >> 2;
  const int slq = tid & 3;
  const int xk = (slq ^ ((sr >> 1) & 3)) << 3;
  const u16* pa = Ab + (size_t)(rm * 256 + sr) * 2048 + xk;
  const u16* pb = Wb + (size_t)(cm * 128 + sr) * 2048 + xk;
  char* const ldsW = (char*)smem + (wid << 10);

  const int xsl = (r16 ^ ((c16 >> 1) & 3)) << 3;
  const int base_a = (wm * 64 + c16) * 32 + xsl;
  const int base_b = 8192 + (wn * 64 + c16) * 32 + xsl;

  f32x4 acc[4][4] = {};

#define STAGE3(slice, slot) do {                                       \
    const u16* sa_ = pa + (slice) * 32;                                \
    const u16* sb_ = pb + (slice) * 32;                                \
    char* d_ = ldsW + (slot) * 24576;                                  \
    GLDS(sa_, d_); GLDS(sa_ + 262144, d_ + 8192);                      \
    GLDS(sb_, d_ + 16384);                                             \
  } while (0)

#define SLICE(s, slot, dostage) do {                                   \
    bf16x8 aX[4], bS[4];                                               \
    _Pragma("unroll")                                                  \
    for (int i = 0; i < 4; ++i)                                        \
      aX[i] = *(const bf16x8*)(smem + (slot) * 12288 + base_a + i * 512); \
    _Pragma("unroll")                                                  \
    for (int j = 0; j < 4; ++j)                                        \
      bS[j] = *(const bf16x8*)(smem + (slot) * 12288 + base_b + j * 512); \
    if (dostage) STAGE3(((s) + 2) & 63, ((s) + 2) % 3);                \
    asm volatile("s_waitcnt vmcnt(3)" ::: "memory");                   \
    __builtin_amdgcn_s_barrier();                                      \
    asm volatile("s_waitcnt lgkmcnt(0)" ::: "memory");                 \
    _Pragma("unroll")                                                  \
    for (int i = 0; i < 4; ++i)                                        \
      _Pragma("unroll")                                                \
      for (int j = 0; j < 4; ++j)                                      \
        acc[i][j] = __builtin_amdgcn_mfma_f32_16x16x32_bf16(           \
            aX[i], bS[j], acc[i][j], 0, 0, 0);                         \
    __builtin_amdgcn_s_barrier();                                      \
  } while (0)

  STAGE3(0, 0); STAGE3(1, 1);
  asm volatile("s_waitcnt vmcnt(3)" ::: "memory");
  __builtin_amdgcn_s_barrier();

  for (int u = 0; u < 21; ++u) {                    // slices 0..62
    const int s0 = u * 3;
    SLICE(s0 + 0, 0, 1);
    SLICE(s0 + 1, 1, 1);
    SLICE(s0 + 2, 2, 1);
  }
  SLICE(63, 0, 0);                                  // peeled last slice
#undef SLICE
#undef STAGE3

  asm volatile("s_waitcnt vmcnt(0)" ::: "memory");
  __builtin_amdgcn_s_barrier();

  float* epi = (float*)smem;
#define EPIPASS(p) do {                                                \
    if ((wm >> 1) == (p)) {                                            \
      _Pragma("unroll")                                                \
      for (int i = 0; i < 4; ++i)                                      \
        _Pragma("unroll")                                              \
        for (int j = 0; j < 4; ++j)                                    \
          _Pragma("unroll")                                            \
          for (int r = 0; r < 4; ++r) {                                \
            float v = acc[i][j][r];                                    \
            v = ((c16 & 3) == 3) ? ftanhf(v) : fsig(v);                \
            epi[((wm & 1) * 64 + i * 16 + r16 * 4 + r) * 128 +         \
                wn * 64 + j * 16 + c16] = v;                           \
          }                                                            \
    }                                                                  \
    __syncthreads();                                                   \
    _Pragma("unroll")                                                  \
    for (int e = 0; e < 2; ++e) {                                      \
      int idx = (e << 9) + tid;                                        \
      int mrow = idx >> 3, q = idx & 7;                                \
      const float* g4 = epi + mrow * 128 + q * 16;                     \
      int rowg = rm * 256 + (p) * 128 + mrow;                          \
      int jgb = cm * 32 + q * 4;                                       \
      int lv = jgb >> 4;                                               \
      float vih = ihp[(rowg << 6) + lv], vfh = fhp[(rowg << 6) + lv];  \
      float wq = vih * vfh;                                            \
      v4f cp4 = *(const v4f*)(cprev + rowg * 1024 + jgb);              \
      float cpv[4] = {cp4.x, cp4.y, cp4.z, cp4.w};                     \
      v4f hv, cv;                                                      \
      _Pragma("unroll")                                                \
      for (int t = 0; t < 4; ++t) {                                    \
        v4f g = *(const v4f*)(g4 + t * 4);                             \
        float iv = g.x, fv = g.y, ov = g.z, gv = g.w;                  \
        float cpx = cpv[t];                                            \
        float c = wq * (fv * cpx + iv * gv) + (vfh - wq) * cpx + (vih - wq) * gv; \
        float h = ov * ftanhf(c);                                      \
        hv[t] = h; cv[t] = c;                                          \
      }                                                                \
      *(v4f*)(out + rowg * 1024 + jgb) = hv;                           \
      *(v4f*)(out + 8388608 + rowg * 1024 + jgb) = cv;                 \
    }                                                                  \
    __syncthreads();                                                   \
  } while (0)
  EPIPASS(0); EPIPASS(1);
#undef EPIPASS
}

// -------------------------------------------------------------- launcher ---
extern "C" void kernel_launch(void* const* d_in, const int* in_sizes, int n_in,
                              void* d_out, int out_size, void* d_ws, size_t ws_size,
                              hipStream_t stream) {
  (void)in_sizes; (void)n_in; (void)out_size; (void)ws_size;
  const float* inp   = (const float*)d_in[0];
  const float* hprev = (const float*)d_in[1];
  const float* cprev = (const float*)d_in[2];
  const float* wl    = (const float*)d_in[3];
  const float* wlev  = (const float*)d_in[4];
  float* out = (float*)d_out;
  char* ws = (char*)d_ws;

  u16* Ahi  = (u16*)(ws);
  u16* Whi  = (u16*)(ws + 67108864);
  u16* Wlo  = (u16*)(ws + 84410368);
  float* ih   = (float*)(ws + 118489088);
  float* fh   = (float*)(ws + 120586240);

  k_convert<<<dim3(2048), dim3(256), 0, stream>>>(inp, hprev, wl, wlev, Ahi, Whi, Wlo);
  k_level_fused<<<dim3(256), dim3(256), 0, stream>>>(Ahi, Whi, Wlo, ih, fh);
  k_gemm_main<<<dim3(1024), dim3(512), 0, stream>>>(Ahi, Whi, cprev, ih, fh, out);
}